// Round 1
// baseline (50.393 us; speedup 1.0000x reference)
//
#include <hip/hip_runtime.h>

// Problem: x[B=8, L=2048, C=64, D=32] f32; zero x[:, s:s+len, ch, :] for 16 blocks.
// Pure masked copy -> memory-bound. 128 MiB in + 128 MiB out => ~43 us roofline @6.3 TB/s.

#define BB 8
#define LL 2048
#define CC 64
#define DD 32
#define NBLK 16

__global__ __launch_bounds__(256) void masking_kernel(
    const float4* __restrict__ x,
    const int* __restrict__ starts,
    const int* __restrict__ lengths,
    const int* __restrict__ channels,
    float4* __restrict__ out,
    int n4)
{
    // Preload the 16 block descriptors into registers (uniform across wave ->
    // compiler emits scalar loads, hoisted out of the loop).
    int st[NBLK], en[NBLK], ch[NBLK];
#pragma unroll
    for (int n = 0; n < NBLK; ++n) {
        st[n] = starts[n];
        en[n] = st[n] + lengths[n];
        ch[n] = channels[n];
    }

    const int stride = gridDim.x * blockDim.x;
    for (int i = blockIdx.x * blockDim.x + threadIdx.x; i < n4; i += stride) {
        // flat float4 index i = ((b*L + l)*C + c)*8 + d4
        const int lc = i >> 3;           // (b*L + l)*C + c
        const int c  = lc & (CC - 1);
        const int l  = (lc >> 6) & (LL - 1);

        bool z = false;
#pragma unroll
        for (int n = 0; n < NBLK; ++n) {
            z |= (c == ch[n]) & (l >= st[n]) & (l < en[n]);
        }
        const float m = z ? 0.0f : 1.0f;

        float4 v = x[i];
        v.x *= m; v.y *= m; v.z *= m; v.w *= m;
        out[i] = v;
    }
}

extern "C" void kernel_launch(void* const* d_in, const int* in_sizes, int n_in,
                              void* d_out, int out_size, void* d_ws, size_t ws_size,
                              hipStream_t stream)
{
    const float4* x      = (const float4*)d_in[0];
    const int* starts    = (const int*)d_in[1];
    const int* lengths   = (const int*)d_in[2];
    const int* channels  = (const int*)d_in[3];
    float4* out          = (float4*)d_out;

    const int n4 = (BB * LL * CC * DD) / 4;   // 8,388,608 float4s
    const int threads = 256;
    const int blocks = 2048;                  // grid-stride; ~8 blocks/CU

    masking_kernel<<<blocks, threads, 0, stream>>>(x, starts, lengths, channels, out, n4);
}

// Round 3
// 46.472 us; speedup vs baseline: 1.0844x; 1.0844x over previous
//
#include <hip/hip_runtime.h>

// Masking: x[B=8, L=2048, C=64, D=32] f32; zero x[:, s:s+len, ch, :] for 16 blocks.
// Memory-bound masked copy. 128 MiB in + 128 MiB out.
// Lever: non-temporal stores (nt flag) so the write-once stream doesn't evict
// the L3-resident input; HBM traffic approaches writes-only.
// Note: __builtin_nontemporal_store needs a native clang vector type, not
// HIP's float4 class -> use ext_vector_type(4) float.

#define BB 8
#define LL 2048
#define CC 64
#define DD 32
#define NBLK 16

typedef float v4f __attribute__((ext_vector_type(4)));

__global__ __launch_bounds__(256) void masking_kernel(
    const v4f* __restrict__ x,
    const int* __restrict__ starts,
    const int* __restrict__ lengths,
    const int* __restrict__ channels,
    v4f* __restrict__ out,
    int n4)
{
    // Block descriptors -> registers (wave-uniform scalar loads, hoisted).
    int st[NBLK], en[NBLK], ch[NBLK];
#pragma unroll
    for (int n = 0; n < NBLK; ++n) {
        st[n] = starts[n];
        en[n] = st[n] + lengths[n];
        ch[n] = channels[n];
    }

    const int stride = gridDim.x * blockDim.x;
    int i = blockIdx.x * blockDim.x + threadIdx.x;

    // 2-way unrolled grid-stride loop: two independent load/mask/store chains.
    for (; i + stride < n4; i += 2 * stride) {
        const int i0 = i;
        const int i1 = i + stride;

        v4f v0 = x[i0];
        v4f v1 = x[i1];

        const int lc0 = i0 >> 3;
        const int c0  = lc0 & (CC - 1);
        const int l0  = (lc0 >> 6) & (LL - 1);
        const int lc1 = i1 >> 3;
        const int c1  = lc1 & (CC - 1);
        const int l1  = (lc1 >> 6) & (LL - 1);

        bool z0 = false, z1 = false;
#pragma unroll
        for (int n = 0; n < NBLK; ++n) {
            z0 |= (c0 == ch[n]) & (l0 >= st[n]) & (l0 < en[n]);
            z1 |= (c1 == ch[n]) & (l1 >= st[n]) & (l1 < en[n]);
        }
        const float m0 = z0 ? 0.0f : 1.0f;
        const float m1 = z1 ? 0.0f : 1.0f;

        __builtin_nontemporal_store(v0 * m0, &out[i0]);
        __builtin_nontemporal_store(v1 * m1, &out[i1]);
    }
    // Tail (at most one element per thread).
    if (i < n4) {
        const int lc = i >> 3;
        const int c  = lc & (CC - 1);
        const int l  = (lc >> 6) & (LL - 1);
        bool z = false;
#pragma unroll
        for (int n = 0; n < NBLK; ++n) {
            z |= (c == ch[n]) & (l >= st[n]) & (l < en[n]);
        }
        const float m = z ? 0.0f : 1.0f;
        v4f v = x[i];
        __builtin_nontemporal_store(v * m, &out[i]);
    }
}

extern "C" void kernel_launch(void* const* d_in, const int* in_sizes, int n_in,
                              void* d_out, int out_size, void* d_ws, size_t ws_size,
                              hipStream_t stream)
{
    const v4f* x         = (const v4f*)d_in[0];
    const int* starts    = (const int*)d_in[1];
    const int* lengths   = (const int*)d_in[2];
    const int* channels  = (const int*)d_in[3];
    v4f* out             = (v4f*)d_out;

    const int n4 = (BB * LL * CC * DD) / 4;   // 8,388,608 float4s
    const int threads = 256;
    const int blocks = 4096;                  // 8 grid-stride iters/thread

    masking_kernel<<<blocks, threads, 0, stream>>>(x, starts, lengths, channels, out, n4);
}